// Round 2
// baseline (168.982 us; speedup 1.0000x reference)
//
#include <hip/hip_runtime.h>
#include <cstdint>
#include <cstring>
#include <map>
#include <string>
#include <vector>
#include <algorithm>

// ---------------------------------------------------------------------------
// Host-side exact replication of numpy default_rng(0) forest generation:
// SeedSequence(0) -> PCG64 -> Generator.integers(0, i) (Lemire, int64 path).
// ---------------------------------------------------------------------------
namespace nprng {

static inline uint32_t hashmix(uint32_t value, uint32_t& hc) {
    value ^= hc;
    hc *= 0x931e8875u;        // MULT_A
    value *= hc;
    value ^= value >> 16;
    return value;
}
static inline uint32_t mixf(uint32_t x, uint32_t y) {
    uint32_t r = x * 0xca01f9ddu - y * 0x4973f715u;  // MIX_MULT_L/R
    r ^= r >> 16;
    return r;
}

struct Pcg64 {
    unsigned __int128 state, inc;
    bool has_uint32;
    uint32_t uinteger;

    static constexpr unsigned __int128 mult() {
        return (((unsigned __int128)2549297995355413924ULL) << 64) |
               4865540595714422341ULL;
    }
    void step() { state = state * mult() + inc; }

    void seed_default0() {
        // SeedSequence(0): entropy=[0], pool_size=4
        uint32_t pool[4] = {0, 0, 0, 0};
        uint32_t hc = 0x43b0d7e5u;  // INIT_A
        for (int i = 0; i < 4; ++i) pool[i] = hashmix(0u, hc);  // entropy[0]=0, pad=0
        for (int isrc = 0; isrc < 4; ++isrc)
            for (int idst = 0; idst < 4; ++idst)
                if (isrc != idst)
                    pool[idst] = mixf(pool[idst], hashmix(pool[isrc], hc));
        // generate_state(4, uint64) -> 8 uint32 words, pool cycled in order
        uint32_t st[8];
        uint32_t hc2 = 0x8b51f9ddu;  // INIT_B
        for (int i = 0; i < 8; ++i) {
            uint32_t dv = pool[i & 3];
            dv ^= hc2;
            hc2 *= 0x58f38dedu;     // MULT_B
            dv *= hc2;
            dv ^= dv >> 16;
            st[i] = dv;
        }
        // view as uint64 little-endian: val[k] = st[2k] | st[2k+1]<<32
        uint64_t v0 = (uint64_t)st[0] | ((uint64_t)st[1] << 32);
        uint64_t v1 = (uint64_t)st[2] | ((uint64_t)st[3] << 32);
        uint64_t v2 = (uint64_t)st[4] | ((uint64_t)st[5] << 32);
        uint64_t v3 = (uint64_t)st[6] | ((uint64_t)st[7] << 32);
        // PCG_128BIT_CONSTANT(high, low): seed = (v0<<64)|v1, inc = (v2<<64)|v3
        unsigned __int128 s = (((unsigned __int128)v0) << 64) | v1;
        unsigned __int128 i_ = (((unsigned __int128)v2) << 64) | v3;
        state = 0;
        inc = (i_ << 1) | 1;
        step();
        state += s;
        step();
        has_uint32 = false;
        uinteger = 0;
    }

    uint64_t next64() {
        step();  // numpy pcg64: step THEN output (XSL-RR)
        uint64_t hi = (uint64_t)(state >> 64);
        uint64_t lo = (uint64_t)state;
        uint64_t x = hi ^ lo;
        unsigned rot = (unsigned)(state >> 122);
        return (x >> rot) | (x << ((64u - rot) & 63u));
    }
    uint32_t next32() {
        if (has_uint32) { has_uint32 = false; return uinteger; }
        uint64_t n = next64();
        has_uint32 = true;
        uinteger = (uint32_t)(n >> 32);   // high half buffered
        return (uint32_t)n;               // low half returned first
    }
    // Lemire bounded in [0, rng] inclusive, rng >= 1 (32-bit path)
    uint32_t bounded_lemire32(uint32_t rng) {
        const uint32_t rng_excl = rng + 1u;
        uint64_t m = (uint64_t)next32() * (uint64_t)rng_excl;
        uint32_t leftover = (uint32_t)m;
        if (leftover < rng_excl) {
            const uint32_t threshold = (0xFFFFFFFFu - rng) % rng_excl;
            while (leftover < threshold) {
                m = (uint64_t)next32() * (uint64_t)rng_excl;
                leftover = (uint32_t)m;
            }
        }
        return (uint32_t)(m >> 32);
    }
    // Generator.integers(0, high), endpoint=False, dtype=int64
    int64_t integers0(int64_t high) {
        uint64_t rng = (uint64_t)(high - 1);
        if (rng == 0) return 0;           // no RNG consumption
        return (int64_t)bounded_lemire32((uint32_t)rng);
    }
};

}  // namespace nprng

// ---------------------------------------------------------------------------
// Plan: deduped tree shapes + per-tree shape ids, built on host each call.
// ---------------------------------------------------------------------------
struct Plan {
    int n_shapes;
    unsigned char shape_of_tree[32];
    unsigned char parent[32][5];   // representative parent array per shape; parent[s][i-1]
    unsigned char leafmask[32];    // bit i set (i=1..5) if node i has no children
    unsigned char firstmask[32];   // bit i set if node i is the max-index child of its parent
};

static std::string canon_node(int node, const std::vector<std::vector<int>>& ch) {
    std::vector<std::string> subs;
    for (int c : ch[node]) subs.push_back(canon_node(c, ch));
    std::sort(subs.begin(), subs.end());
    std::string r = "(";
    for (auto& s : subs) r += s;
    r += ")";
    return r;
}

// ---------------------------------------------------------------------------
// Device kernel. One 256-thread block per (b,c); thread owns 16 contiguous t.
// T~ per shape via register-resident series + block exclusive scans.
// ---------------------------------------------------------------------------
__device__ __forceinline__ void block_excl_scan(const float (&A)[16], float (&E)[16],
                                                float (*s_part)[4], int& ctr,
                                                const int lane, const int wv) {
    float loc[16];
    float run = 0.f;
#pragma unroll
    for (int j = 0; j < 16; ++j) { run += A[j]; loc[j] = run; }
    const float tot = run;
    float w = tot;
#pragma unroll
    for (int d = 1; d < 64; d <<= 1) {
        float o = __shfl_up(w, (unsigned)d, 64);
        if (lane >= d) w += o;
    }
    const int slot = ctr & 3;  ++ctr;   // rotating slots: 1 barrier per scan, WAR-safe
    if (lane == 63) s_part[slot][wv] = w;
    __syncthreads();
    float base = w - tot;               // wave-exclusive offset for this lane
#pragma unroll
    for (int k = 0; k < 3; ++k)
        if (k < wv) base += s_part[slot][k];
    E[0] = base;
#pragma unroll
    for (int j = 1; j < 16; ++j) E[j] = base + loc[j - 1];
}

__device__ __forceinline__ void apply_one(float (&PP)[16], const float (&E)[16],
                                          const float (&xr)[16], const bool first) {
    if (first) {
#pragma unroll
        for (int j = 0; j < 16; ++j) PP[j] = xr[j] * E[j];
    } else {
#pragma unroll
        for (int j = 0; j < 16; ++j) PP[j] *= E[j];
    }
}

__device__ __forceinline__ void apply_to(const int p,
        float (&P0)[16], float (&P1)[16], float (&P2)[16], float (&P3)[16], float (&P4)[16],
        const float (&E)[16], const float (&xr)[16], const bool first) {
    switch (p) {  // p is block-uniform
        case 0: apply_one(P0, E, xr, first); break;
        case 1: apply_one(P1, E, xr, first); break;
        case 2: apply_one(P2, E, xr, first); break;
        case 3: apply_one(P3, E, xr, first); break;
        default: apply_one(P4, E, xr, first); break;
    }
}

__global__ __launch_bounds__(256) void fis_kernel(const float* __restrict__ x,
                                                  const float* __restrict__ alphas,
                                                  float* __restrict__ out,
                                                  const Plan plan) {
    const int tid = threadIdx.x;
    const int lane = tid & 63;
    const int wv = tid >> 6;
    const int bc = blockIdx.x;
    const int b = bc >> 7;     // CH = 128
    const int c = bc & 127;

    __shared__ float s_part[4][4];
    __shared__ float s_T[32];

    float xr[16];
    {
        const float4* xv = reinterpret_cast<const float4*>(
            x + (((size_t)b << 7) + (size_t)c) * 4096 + (size_t)tid * 16);
#pragma unroll
        for (int j = 0; j < 4; ++j) {
            const float4 v = xv[j];
            xr[4 * j + 0] = v.x; xr[4 * j + 1] = v.y;
            xr[4 * j + 2] = v.z; xr[4 * j + 3] = v.w;
        }
    }

    int ctr = 0;
    float E5[16];  // exclusive cumsum of x: shared by every leaf node of every shape
    block_excl_scan(xr, E5, s_part, ctr, lane, wv);

    for (int s = 0; s < plan.n_shapes; ++s) {
        float P0[16], P1[16], P2[16], P3[16], P4[16];
        const int lm = plan.leafmask[s];
        const int fm = plan.firstmask[s];

        // node 5: always a leaf (children have larger index)
        apply_to(plan.parent[s][4], P0, P1, P2, P3, P4, E5, xr, ((fm >> 5) & 1) != 0);

#define PROC_NODE(i, PI)                                                         \
        {                                                                        \
            const bool lf = ((lm >> (i)) & 1) != 0;                              \
            const bool fst = ((fm >> (i)) & 1) != 0;                             \
            const int p = plan.parent[s][(i) - 1];                               \
            if (lf) {                                                            \
                apply_to(p, P0, P1, P2, P3, P4, E5, xr, fst);                    \
            } else {                                                             \
                float E[16];                                                     \
                block_excl_scan(PI, E, s_part, ctr, lane, wv);                   \
                apply_to(p, P0, P1, P2, P3, P4, E, xr, fst);                     \
            }                                                                    \
        }
        PROC_NODE(4, P4)
        PROC_NODE(3, P3)
        PROC_NODE(2, P2)
        PROC_NODE(1, P1)
#undef PROC_NODE

        // reduce: T~[s] = sum_t P0[t]
        float r = 0.f;
#pragma unroll
        for (int j = 0; j < 16; ++j) r += P0[j];
#pragma unroll
        for (int d = 1; d < 64; d <<= 1) r += __shfl_xor(r, d, 64);
        const int slot = ctr & 3;  ++ctr;
        if (lane == 0) s_part[slot][wv] = r;
        __syncthreads();
        if (tid == 0)
            s_T[s] = s_part[slot][0] + s_part[slot][1] + s_part[slot][2] + s_part[slot][3];
    }

    __syncthreads();
    if (tid < 32) {
        const int tree = tid;
        const float* ap = alphas + tree * 768 + c;  // alphas[tree, i, c], [32,6,128]
        const float aprod = ap[0] * ap[128] * ap[256] * ap[384] * ap[512] * ap[640];
        out[(((size_t)b << 5) + tree) * 128 + c] = aprod * s_T[plan.shape_of_tree[tree]];
    }
}

// ---------------------------------------------------------------------------
extern "C" void kernel_launch(void* const* d_in, const int* in_sizes, int n_in,
                              void* d_out, int out_size, void* d_ws, size_t ws_size,
                              hipStream_t stream) {
    const float* x = (const float*)d_in[0];       // [16,128,4096] f32
    const float* alphas = (const float*)d_in[1];  // [32,6,128]    f32
    float* out = (float*)d_out;                   // [16,32,128]   f32

    // Deterministic host-side plan construction (pure CPU, graph-capture safe).
    Plan plan;
    std::memset(&plan, 0, sizeof(plan));
    plan.n_shapes = 0;

    nprng::Pcg64 rng;
    rng.seed_default0();
    std::map<std::string, int> ids;
    for (int t = 0; t < 32; ++t) {
        int par[5];
        for (int i = 1; i <= 5; ++i) par[i - 1] = (int)rng.integers0(i);
        std::vector<std::vector<int>> ch(6);
        for (int i = 1; i <= 5; ++i) ch[par[i - 1]].push_back(i);
        const std::string key = canon_node(0, ch);
        int id;
        auto it = ids.find(key);
        if (it == ids.end()) {
            id = plan.n_shapes++;
            ids.emplace(key, id);
            unsigned char lm = 0, fm = 0;
            for (int i = 1; i <= 5; ++i) {
                plan.parent[id][i - 1] = (unsigned char)par[i - 1];
                if (ch[i].empty()) lm |= (unsigned char)(1u << i);
            }
            for (int p = 0; p < 6; ++p)
                if (!ch[p].empty()) fm |= (unsigned char)(1u << ch[p].back());
            plan.leafmask[id] = lm;
            plan.firstmask[id] = fm;
        } else {
            id = it->second;
        }
        plan.shape_of_tree[t] = (unsigned char)id;
    }

    fis_kernel<<<dim3(16 * 128), dim3(256), 0, stream>>>(x, alphas, out, plan);
}

// Round 3
// 163.067 us; speedup vs baseline: 1.0363x; 1.0363x over previous
//
#include <hip/hip_runtime.h>
#include <cstdint>
#include <cstring>
#include <map>
#include <string>
#include <vector>
#include <algorithm>

// ---------------------------------------------------------------------------
// Host-side exact replication of numpy default_rng(0) forest generation:
// SeedSequence(0) -> PCG64 -> Generator.integers(0, i) (Lemire, int64 path).
// ---------------------------------------------------------------------------
namespace nprng {

static inline uint32_t hashmix(uint32_t value, uint32_t& hc) {
    value ^= hc;
    hc *= 0x931e8875u;        // MULT_A
    value *= hc;
    value ^= value >> 16;
    return value;
}
static inline uint32_t mixf(uint32_t x, uint32_t y) {
    uint32_t r = x * 0xca01f9ddu - y * 0x4973f715u;  // MIX_MULT_L/R
    r ^= r >> 16;
    return r;
}

struct Pcg64 {
    unsigned __int128 state, inc;
    bool has_uint32;
    uint32_t uinteger;

    static constexpr unsigned __int128 mult() {
        return (((unsigned __int128)2549297995355413924ULL) << 64) |
               4865540595714422341ULL;
    }
    void step() { state = state * mult() + inc; }

    void seed_default0() {
        uint32_t pool[4] = {0, 0, 0, 0};
        uint32_t hc = 0x43b0d7e5u;  // INIT_A
        for (int i = 0; i < 4; ++i) pool[i] = hashmix(0u, hc);
        for (int isrc = 0; isrc < 4; ++isrc)
            for (int idst = 0; idst < 4; ++idst)
                if (isrc != idst)
                    pool[idst] = mixf(pool[idst], hashmix(pool[isrc], hc));
        uint32_t st[8];
        uint32_t hc2 = 0x8b51f9ddu;  // INIT_B
        for (int i = 0; i < 8; ++i) {
            uint32_t dv = pool[i & 3];
            dv ^= hc2;
            hc2 *= 0x58f38dedu;     // MULT_B
            dv *= hc2;
            dv ^= dv >> 16;
            st[i] = dv;
        }
        uint64_t v0 = (uint64_t)st[0] | ((uint64_t)st[1] << 32);
        uint64_t v1 = (uint64_t)st[2] | ((uint64_t)st[3] << 32);
        uint64_t v2 = (uint64_t)st[4] | ((uint64_t)st[5] << 32);
        uint64_t v3 = (uint64_t)st[6] | ((uint64_t)st[7] << 32);
        unsigned __int128 s = (((unsigned __int128)v0) << 64) | v1;
        unsigned __int128 i_ = (((unsigned __int128)v2) << 64) | v3;
        state = 0;
        inc = (i_ << 1) | 1;
        step();
        state += s;
        step();
        has_uint32 = false;
        uinteger = 0;
    }

    uint64_t next64() {
        step();  // numpy pcg64: step THEN output (XSL-RR)
        uint64_t hi = (uint64_t)(state >> 64);
        uint64_t lo = (uint64_t)state;
        uint64_t x = hi ^ lo;
        unsigned rot = (unsigned)(state >> 122);
        return (x >> rot) | (x << ((64u - rot) & 63u));
    }
    uint32_t next32() {
        if (has_uint32) { has_uint32 = false; return uinteger; }
        uint64_t n = next64();
        has_uint32 = true;
        uinteger = (uint32_t)(n >> 32);
        return (uint32_t)n;
    }
    uint32_t bounded_lemire32(uint32_t rng) {
        const uint32_t rng_excl = rng + 1u;
        uint64_t m = (uint64_t)next32() * (uint64_t)rng_excl;
        uint32_t leftover = (uint32_t)m;
        if (leftover < rng_excl) {
            const uint32_t threshold = (0xFFFFFFFFu - rng) % rng_excl;
            while (leftover < threshold) {
                m = (uint64_t)next32() * (uint64_t)rng_excl;
                leftover = (uint32_t)m;
            }
        }
        return (uint32_t)(m >> 32);
    }
    int64_t integers0(int64_t high) {
        uint64_t rng = (uint64_t)(high - 1);
        if (rng == 0) return 0;  // no RNG consumption
        return (int64_t)bounded_lemire32((uint32_t)rng);
    }
};

}  // namespace nprng

// ---------------------------------------------------------------------------
// Plan: deduped tree shapes, bin-packed into NGROUPS groups (gridDim.y).
// ---------------------------------------------------------------------------
#define NGROUPS 4

struct GroupPlan {
    int n_shapes;
    int n_trees;
    unsigned char parent[20][5];
    unsigned char leafmask[20];
    unsigned char firstmask[20];
    unsigned char tree_id[32];
    unsigned char tree_shape[32];  // local shape index within this group
};
struct Plan {
    GroupPlan g[NGROUPS];
};

static std::string canon_node(int node, const std::vector<std::vector<int>>& ch) {
    std::vector<std::string> subs;
    for (int c : ch[node]) subs.push_back(canon_node(c, ch));
    std::sort(subs.begin(), subs.end());
    std::string r = "(";
    for (auto& s : subs) r += s;
    r += ")";
    return r;
}

// ---------------------------------------------------------------------------
// Device: DPP wave scan (canonical gfx9 sequence: row_shr 1/2/4/8 +
// row_bcast15 -> rows{1,3} + row_bcast31 -> rows{2,3}). Pure VALU, no LDS.
// ---------------------------------------------------------------------------
template <int CTRL, int RM>
__device__ __forceinline__ float dppmov(float x) {
    return __builtin_bit_cast(float,
        __builtin_amdgcn_update_dpp(0, __builtin_bit_cast(int, x), CTRL, RM, 0xf, false));
}

__device__ __forceinline__ float wave_incl_scan(float v) {
    v += dppmov<0x111, 0xf>(v);  // row_shr:1
    v += dppmov<0x112, 0xf>(v);  // row_shr:2
    v += dppmov<0x114, 0xf>(v);  // row_shr:4
    v += dppmov<0x118, 0xf>(v);  // row_shr:8
    v += dppmov<0x142, 0xa>(v);  // row_bcast:15 -> rows 1,3
    v += dppmov<0x143, 0xc>(v);  // row_bcast:31 -> rows 2,3
    return v;                    // inclusive scan over 64 lanes; lane63 = total
}

__device__ __forceinline__ void block_excl_scan(const float (&A)[16], float (&E)[16],
                                                float (*s_part)[4], int& ctr,
                                                const int lane, const int wv) {
    float loc[16];
    float run = 0.f;
#pragma unroll
    for (int j = 0; j < 16; ++j) { run += A[j]; loc[j] = run; }
    const float tot = run;
    const float w = wave_incl_scan(tot);       // inclusive over this wave's 64 totals
    const int slot = ctr & 3;  ++ctr;          // rotating slots: 1 barrier per scan
    if (lane == 63) s_part[slot][wv] = w;      // wave total
    __syncthreads();
    float base = w - tot;                      // exclusive offset within wave
#pragma unroll
    for (int k = 0; k < 3; ++k)
        if (k < wv) base += s_part[slot][k];
    E[0] = base;
#pragma unroll
    for (int j = 1; j < 16; ++j) E[j] = base + loc[j - 1];
}

__device__ __forceinline__ void apply_one(float (&PP)[16], const float (&E)[16],
                                          const float (&xr)[16], const bool first) {
    if (first) {
#pragma unroll
        for (int j = 0; j < 16; ++j) PP[j] = xr[j] * E[j];
    } else {
#pragma unroll
        for (int j = 0; j < 16; ++j) PP[j] *= E[j];
    }
}

__device__ __forceinline__ void apply_to(const int p,
        float (&P0)[16], float (&P1)[16], float (&P2)[16], float (&P3)[16], float (&P4)[16],
        const float (&E)[16], const float (&xr)[16], const bool first) {
    switch (p) {  // p is block-uniform
        case 0: apply_one(P0, E, xr, first); break;
        case 1: apply_one(P1, E, xr, first); break;
        case 2: apply_one(P2, E, xr, first); break;
        case 3: apply_one(P3, E, xr, first); break;
        default: apply_one(P4, E, xr, first); break;
    }
}

__global__ __launch_bounds__(256) void fis_kernel(const float* __restrict__ x,
                                                  const float* __restrict__ alphas,
                                                  float* __restrict__ out,
                                                  const Plan plan) {
    const int tid = threadIdx.x;
    const int lane = tid & 63;
    const int wv = tid >> 6;
    const int bc = blockIdx.x;
    const int b = bc >> 7;     // CH = 128
    const int c = bc & 127;
    const GroupPlan& gp = plan.g[blockIdx.y];
    if (gp.n_trees == 0) return;   // uniform early-out for empty groups

    __shared__ float s_part[4][4];
    __shared__ float s_T[20];

    float xr[16];
    {
        const float4* xv = reinterpret_cast<const float4*>(
            x + (((size_t)b << 7) + (size_t)c) * 4096 + (size_t)tid * 16);
#pragma unroll
        for (int j = 0; j < 4; ++j) {
            const float4 v = xv[j];
            xr[4 * j + 0] = v.x; xr[4 * j + 1] = v.y;
            xr[4 * j + 2] = v.z; xr[4 * j + 3] = v.w;
        }
    }

    int ctr = 0;
    float E5[16];  // exclusive cumsum of x: shared by every leaf of every shape
    block_excl_scan(xr, E5, s_part, ctr, lane, wv);

    for (int s = 0; s < gp.n_shapes; ++s) {
        float P0[16], P1[16], P2[16], P3[16], P4[16];
        const int lm = gp.leafmask[s];
        const int fm = gp.firstmask[s];

        // node 5: always a leaf (children have larger index)
        apply_to(gp.parent[s][4], P0, P1, P2, P3, P4, E5, xr, ((fm >> 5) & 1) != 0);

#define PROC_NODE(i, PI)                                                         \
        {                                                                        \
            const bool lf = ((lm >> (i)) & 1) != 0;                              \
            const bool fst = ((fm >> (i)) & 1) != 0;                             \
            const int p = gp.parent[s][(i) - 1];                                 \
            if (lf) {                                                            \
                apply_to(p, P0, P1, P2, P3, P4, E5, xr, fst);                    \
            } else {                                                             \
                float E[16];                                                     \
                block_excl_scan(PI, E, s_part, ctr, lane, wv);                   \
                apply_to(p, P0, P1, P2, P3, P4, E, xr, fst);                     \
            }                                                                    \
        }
        PROC_NODE(4, P4)
        PROC_NODE(3, P3)
        PROC_NODE(2, P2)
        PROC_NODE(1, P1)
#undef PROC_NODE

        // reduce: T~[s] = sum_t P0[t]
        float r = 0.f;
#pragma unroll
        for (int j = 0; j < 16; ++j) r += P0[j];
        const float w = wave_incl_scan(r);     // lane63 = wave total
        const int slot = ctr & 3;  ++ctr;
        if (lane == 63) s_part[slot][wv] = w;
        __syncthreads();
        if (tid == 0)
            s_T[s] = s_part[slot][0] + s_part[slot][1] + s_part[slot][2] + s_part[slot][3];
    }

    __syncthreads();
    if (tid < gp.n_trees) {
        const int tree = gp.tree_id[tid];
        const float* ap = alphas + tree * 768 + c;  // alphas[tree, i, c], [32,6,128]
        const float aprod = ap[0] * ap[128] * ap[256] * ap[384] * ap[512] * ap[640];
        out[(((size_t)b << 5) + tree) * 128 + c] = aprod * s_T[gp.tree_shape[tid]];
    }
}

// ---------------------------------------------------------------------------
extern "C" void kernel_launch(void* const* d_in, const int* in_sizes, int n_in,
                              void* d_out, int out_size, void* d_ws, size_t ws_size,
                              hipStream_t stream) {
    const float* x = (const float*)d_in[0];       // [16,128,4096] f32
    const float* alphas = (const float*)d_in[1];  // [32,6,128]    f32
    float* out = (float*)d_out;                   // [16,32,128]   f32

    // ---- deterministic host-side plan (pure CPU, graph-capture safe) ----
    struct SH { int par[5]; unsigned char lm, fm; int cost; std::vector<int> trees; };
    std::vector<SH> shapes;
    std::map<std::string, int> ids;

    nprng::Pcg64 rng;
    rng.seed_default0();
    for (int t = 0; t < 32; ++t) {
        int par[5];
        for (int i = 1; i <= 5; ++i) par[i - 1] = (int)rng.integers0(i);
        std::vector<std::vector<int>> ch(6);
        for (int i = 1; i <= 5; ++i) ch[par[i - 1]].push_back(i);
        const std::string key = canon_node(0, ch);
        auto it = ids.find(key);
        int id;
        if (it == ids.end()) {
            id = (int)shapes.size();
            ids.emplace(key, id);
            SH sh;
            unsigned char lm = 0, fm = 0;
            int nscan = 0;
            for (int i = 1; i <= 5; ++i) {
                sh.par[i - 1] = par[i - 1];
                if (ch[i].empty()) lm |= (unsigned char)(1u << i);
                else ++nscan;
            }
            for (int p = 0; p < 6; ++p)
                if (!ch[p].empty()) fm |= (unsigned char)(1u << ch[p].back());
            sh.lm = lm; sh.fm = fm;
            sh.cost = nscan + 1;  // scans + reduce
            shapes.push_back(sh);
        } else {
            id = it->second;
        }
        shapes[id].trees.push_back(t);
    }

    // greedy bin-pack shapes (desc by cost) into NGROUPS groups
    std::vector<int> order(shapes.size());
    for (size_t i = 0; i < shapes.size(); ++i) order[i] = (int)i;
    std::sort(order.begin(), order.end(),
              [&](int a, int bq) { return shapes[a].cost > shapes[bq].cost; });
    Plan plan;
    std::memset(&plan, 0, sizeof(plan));
    int load[NGROUPS] = {0};
    for (int idx : order) {
        int g = 0;
        for (int k = 1; k < NGROUPS; ++k)
            if (load[k] < load[g]) g = k;
        load[g] += shapes[idx].cost;
        GroupPlan& G = plan.g[g];
        const int ls = G.n_shapes++;
        for (int i = 0; i < 5; ++i) G.parent[ls][i] = (unsigned char)shapes[idx].par[i];
        G.leafmask[ls] = shapes[idx].lm;
        G.firstmask[ls] = shapes[idx].fm;
        for (int t : shapes[idx].trees) {
            G.tree_id[G.n_trees] = (unsigned char)t;
            G.tree_shape[G.n_trees] = (unsigned char)ls;
            ++G.n_trees;
        }
    }

    fis_kernel<<<dim3(16 * 128, NGROUPS), dim3(256), 0, stream>>>(x, alphas, out, plan);
}

// Round 4
// 19.788 us; speedup vs baseline: 8.5397x; 8.2408x over previous
//
#include <hip/hip_runtime.h>
#include <cstdint>
#include <cstddef>

// ===========================================================================
// Compile-time replication of numpy default_rng(0) forest generation
// (SeedSequence(0) -> PCG64 -> Generator.integers(0,i), Lemire int64 path).
// Validated on-HW in rounds 2-3 (absmax 4.2e6 vs 1.04e12 threshold).
// ===========================================================================
namespace cx {

constexpr uint32_t hashmix(uint32_t value, uint32_t& hc) {
    value ^= hc; hc *= 0x931e8875u; value *= hc; value ^= value >> 16; return value;
}
constexpr uint32_t mixf(uint32_t x, uint32_t y) {
    uint32_t r = x * 0xca01f9ddu - y * 0x4973f715u; r ^= r >> 16; return r;
}

struct Pcg64 {
    unsigned __int128 state{}, inc{};
    bool has_uint32{}; uint32_t uinteger{};
    static constexpr unsigned __int128 mult() {
        return (((unsigned __int128)2549297995355413924ULL) << 64) | 4865540595714422341ULL;
    }
    constexpr void step() { state = state * mult() + inc; }
    constexpr void seed_default0() {
        uint32_t pool[4] = {0, 0, 0, 0};
        uint32_t hc = 0x43b0d7e5u;  // INIT_A
        for (int i = 0; i < 4; ++i) pool[i] = hashmix(0u, hc);
        for (int isrc = 0; isrc < 4; ++isrc)
            for (int idst = 0; idst < 4; ++idst)
                if (isrc != idst) pool[idst] = mixf(pool[idst], hashmix(pool[isrc], hc));
        uint32_t st[8] = {};
        uint32_t hc2 = 0x8b51f9ddu;  // INIT_B
        for (int i = 0; i < 8; ++i) {
            uint32_t dv = pool[i & 3];
            dv ^= hc2; hc2 *= 0x58f38dedu; dv *= hc2; dv ^= dv >> 16;
            st[i] = dv;
        }
        const uint64_t v0 = (uint64_t)st[0] | ((uint64_t)st[1] << 32);
        const uint64_t v1 = (uint64_t)st[2] | ((uint64_t)st[3] << 32);
        const uint64_t v2 = (uint64_t)st[4] | ((uint64_t)st[5] << 32);
        const uint64_t v3 = (uint64_t)st[6] | ((uint64_t)st[7] << 32);
        const unsigned __int128 s = (((unsigned __int128)v0) << 64) | v1;
        const unsigned __int128 i_ = (((unsigned __int128)v2) << 64) | v3;
        state = 0; inc = (i_ << 1) | 1;
        step(); state += s; step();
        has_uint32 = false; uinteger = 0;
    }
    constexpr uint64_t next64() {
        step();
        const uint64_t hi = (uint64_t)(state >> 64), lo = (uint64_t)state;
        const uint64_t x = hi ^ lo;
        const unsigned rot = (unsigned)(state >> 122);
        return (x >> rot) | (x << ((64u - rot) & 63u));
    }
    constexpr uint32_t next32() {
        if (has_uint32) { has_uint32 = false; return uinteger; }
        const uint64_t n = next64();
        has_uint32 = true; uinteger = (uint32_t)(n >> 32);
        return (uint32_t)n;
    }
    constexpr uint32_t bounded_lemire32(uint32_t rng) {
        const uint32_t rng_excl = rng + 1u;
        uint64_t m = (uint64_t)next32() * (uint64_t)rng_excl;
        uint32_t leftover = (uint32_t)m;
        if (leftover < rng_excl) {
            const uint32_t threshold = (0xFFFFFFFFu - rng) % rng_excl;
            while (leftover < threshold) {
                m = (uint64_t)next32() * (uint64_t)rng_excl;
                leftover = (uint32_t)m;
            }
        }
        return (uint32_t)(m >> 32);
    }
    constexpr int64_t integers0(int64_t high) {
        const uint64_t rng = (uint64_t)(high - 1);
        if (rng == 0) return 0;  // no RNG consumption
        return (int64_t)bounded_lemire32((uint32_t)rng);
    }
};

// ===========================================================================
// Compile-time plan: distinct proper-subtree series (each = one scan, computed
// once for the WHOLE forest), root formulas, levels, and liveness-based slot
// allocation. Series value: w_s = x * prod_{children} C_child; C_s = exclusive
// cumsum of w_s. Root: T~_r = sum_t x * prod C_child. Series 0 = leaf (C0=E5).
// ===========================================================================
constexpr int NTREE = 32, MAXSER = 32, MAXROOT = 32, MAXFAC = 5, MAXSLOT = 12;

struct Plan {
    int nser, nroot, nslot, maxlvl;
    int lvl[MAXSER];
    int slot[MAXSER];
    int nfac[MAXSER];
    int fac[MAXSER][4];
    int rnfac[MAXROOT];
    int rfac[MAXROOT][MAXFAC];
    int rlvl[MAXROOT];
    int tree_root[NTREE];
};

constexpr Plan build_plan() {
    Plan P{};
    unsigned skey[MAXSER] = {}, rkey[MAXROOT] = {};
    P.nser = 1; skey[0] = (2u << 16) | 2u;  // leaf canonical code "10"
    P.nfac[0] = 0;
    P.nroot = 0;

    Pcg64 rng; rng.seed_default0();
    for (int t = 0; t < NTREE; ++t) {
        int par[6] = {0, 0, 0, 0, 0, 0};
        for (int i = 1; i <= 5; ++i) par[i] = (int)rng.integers0(i);
        int ch[6][5] = {}; int nch[6] = {};
        for (int i = 1; i <= 5; ++i) ch[par[i]][nch[par[i]]++] = i;

        int sid[6] = {}; unsigned keyn[6] = {};
        for (int i = 5; i >= 1; --i) {
            const int n = nch[i];
            unsigned ck[5] = {}; int cf[5] = {};
            for (int k = 0; k < n; ++k) { ck[k] = keyn[ch[i][k]]; cf[k] = sid[ch[i][k]]; }
            for (int a = 0; a < n; ++a)   // sort keys desc (canonical), ids asc (product order)
                for (int bq = a + 1; bq < n; ++bq) {
                    if (ck[bq] > ck[a]) { unsigned tmp = ck[a]; ck[a] = ck[bq]; ck[bq] = tmp; }
                    if (cf[bq] < cf[a]) { int tmp = cf[a]; cf[a] = cf[bq]; cf[bq] = tmp; }
                }
            unsigned bits = 1u, len = 1u;
            for (int k = 0; k < n; ++k) { bits = (bits << (ck[k] >> 16)) | (ck[k] & 0xffffu); len += ck[k] >> 16; }
            bits <<= 1; len += 1;
            const unsigned key = (len << 16) | bits;
            keyn[i] = key;
            int id = -1;
            for (int q = 0; q < P.nser; ++q) if (skey[q] == key) { id = q; break; }
            if (id < 0) {
                id = P.nser++;
                skey[id] = key; P.nfac[id] = n;
                for (int k = 0; k < n; ++k) P.fac[id][k] = cf[k];
            }
            sid[i] = id;
        }
        {   // root shape
            const int n = nch[0];
            unsigned ck[5] = {}; int cf[5] = {};
            for (int k = 0; k < n; ++k) { ck[k] = keyn[ch[0][k]]; cf[k] = sid[ch[0][k]]; }
            for (int a = 0; a < n; ++a)
                for (int bq = a + 1; bq < n; ++bq) {
                    if (ck[bq] > ck[a]) { unsigned tmp = ck[a]; ck[a] = ck[bq]; ck[bq] = tmp; }
                    if (cf[bq] < cf[a]) { int tmp = cf[a]; cf[a] = cf[bq]; cf[bq] = tmp; }
                }
            unsigned bits = 1u, len = 1u;
            for (int k = 0; k < n; ++k) { bits = (bits << (ck[k] >> 16)) | (ck[k] & 0xffffu); len += ck[k] >> 16; }
            bits <<= 1; len += 1;
            const unsigned key = (len << 16) | bits;
            int id = -1;
            for (int q = 0; q < P.nroot; ++q) if (rkey[q] == key) { id = q; break; }
            if (id < 0) {
                id = P.nroot++;
                rkey[id] = key; P.rnfac[id] = n;
                for (int k = 0; k < n; ++k) P.rfac[id][k] = cf[k];
            }
            P.tree_root[t] = id;
        }
    }
    // levels (factors always have smaller id -> single pass)
    P.lvl[0] = 0; P.maxlvl = 0;
    for (int s = 1; s < P.nser; ++s) {
        int m = 0;
        for (int k = 0; k < P.nfac[s]; ++k) { const int l = P.lvl[P.fac[s][k]]; if (l > m) m = l; }
        P.lvl[s] = m + 1;
        if (m + 1 > P.maxlvl) P.maxlvl = m + 1;
    }
    for (int r = 0; r < P.nroot; ++r) {
        int m = 0;
        for (int k = 0; k < P.rnfac[r]; ++k) { const int l = P.lvl[P.rfac[r][k]]; if (l > m) m = l; }
        P.rlvl[r] = m;
    }
    // last-use level per series (scan consumers at pre-phase lvl, reduces after post rlvl)
    int last[MAXSER] = {};
    for (int s = 0; s < P.nser; ++s) last[s] = 0;
    for (int s = 1; s < P.nser; ++s)
        for (int k = 0; k < P.nfac[s]; ++k) { const int f = P.fac[s][k]; if (P.lvl[s] > last[f]) last[f] = P.lvl[s]; }
    for (int r = 0; r < P.nroot; ++r)
        for (int k = 0; k < P.rnfac[r]; ++k) { const int f = P.rfac[r][k]; if (P.rlvl[r] > last[f]) last[f] = P.rlvl[r]; }
    // greedy slot allocation; slot reusable at level >= free_at (last_use+1: safe
    // under program order [pre L][bar][post L][reduces L] with dst written pre-phase)
    int free_at[MAXSLOT] = {};
    for (int q = 0; q < MAXSLOT; ++q) free_at[q] = -1000;
    P.nslot = 0;
    for (int L = 0; L <= P.maxlvl; ++L)
        for (int s = 0; s < P.nser; ++s) {
            if (P.lvl[s] != L) continue;
            int pick = -1;
            for (int q = 0; q < MAXSLOT; ++q) if (free_at[q] <= L) { pick = q; break; }
            P.slot[s] = pick;
            free_at[pick] = last[s] + 1;
            if (pick + 1 > P.nslot) P.nslot = pick + 1;
        }
    return P;
}

constexpr Plan PL = build_plan();
static_assert(PL.nser <= MAXSER && PL.nroot <= MAXROOT, "plan overflow");
static_assert(PL.nslot <= MAXSLOT && PL.maxlvl <= 9, "plan overflow");
static_assert(PL.nslot >= 1 && PL.nser >= 1 && PL.nroot >= 1, "plan degenerate");

}  // namespace cx

// ===========================================================================
// Device: DPP wave scan (gfx9 canonical: row_shr 1/2/4/8 + row_bcast 15/31).
// ===========================================================================
template <int CTRL, int RM>
__device__ __forceinline__ float dppmov(float x) {
    return __builtin_bit_cast(float,
        __builtin_amdgcn_update_dpp(0, __builtin_bit_cast(int, x), CTRL, RM, 0xf, false));
}
__device__ __forceinline__ float wave_incl_scan(float v) {
    v += dppmov<0x111, 0xf>(v);
    v += dppmov<0x112, 0xf>(v);
    v += dppmov<0x114, 0xf>(v);
    v += dppmov<0x118, 0xf>(v);
    v += dppmov<0x142, 0xa>(v);  // row_bcast:15 -> rows 1,3
    v += dppmov<0x143, 0xc>(v);  // row_bcast:31 -> rows 2,3
    return v;                    // inclusive; lane63 = wave total
}

struct OutMap { unsigned char m[32]; };

// ===========================================================================
// Fully-unrolled straight-line kernel generated from the constexpr plan.
// One 256-thread block per (b,c); thread owns 16 contiguous t.
// Program: for L in 0..maxlvl: [pre: build w, local cumsum->dst slot, DPP,
// wave-total->LDS] barrier [post: base + in-place shift -> exclusive E]
// [reduces at rlvl L -> per-wave partials in LDS]; final barrier; output.
// ===========================================================================
__global__ __launch_bounds__(256) void fis_kernel(const float* __restrict__ x,
                                                  const float* __restrict__ alphas,
                                                  float* __restrict__ out,
                                                  const OutMap om) {
    using cx::PL;
    constexpr int NSER = PL.nser, NROOT = PL.nroot, NSLOT = PL.nslot, MAXL = PL.maxlvl;

    const int tid = threadIdx.x;
    const int lane = tid & 63;
    const int wv = tid >> 6;
    const int b = blockIdx.x >> 7;   // CH = 128
    const int c = blockIdx.x & 127;

    __shared__ float s_w[NSER + NROOT][4];

    float xr[16];
    {
        const float4* xv = reinterpret_cast<const float4*>(
            x + (((size_t)b << 7) + (size_t)c) * 4096 + (size_t)tid * 16);
#pragma unroll
        for (int j = 0; j < 4; ++j) {
            const float4 v = xv[j];
            xr[4 * j + 0] = v.x; xr[4 * j + 1] = v.y;
            xr[4 * j + 2] = v.z; xr[4 * j + 3] = v.w;
        }
    }

    float S[NSLOT][16];   // all indices compile-time after unroll -> registers
    float tots[NSER], winc[NSER];

#pragma unroll
    for (int L = 0; L <= MAXL; ++L) {
        // ---- pre-phase: scans at level L ----
#pragma unroll
        for (int s = 0; s < NSER; ++s) {
            if (PL.lvl[s] != L) continue;
            constexpr auto& slot = PL.slot;
            const int ds = slot[s];
            float w[16];
#pragma unroll
            for (int j = 0; j < 16; ++j) w[j] = xr[j];
#pragma unroll
            for (int k = 0; k < 4; ++k) {
                if (k < PL.nfac[s]) {
                    const int fs = slot[PL.fac[s][k]];
#pragma unroll
                    for (int j = 0; j < 16; ++j) w[j] *= S[fs][j];
                }
            }
            float run = 0.f;
#pragma unroll
            for (int j = 0; j < 16; ++j) { run += w[j]; S[ds][j] = run; }  // local inclusive
            tots[s] = run;
            winc[s] = wave_incl_scan(run);
            if (lane == 63) s_w[s][wv] = winc[s];
        }
        __syncthreads();
        // ---- post-phase: finish exclusive cumsum ----
#pragma unroll
        for (int s = 0; s < NSER; ++s) {
            if (PL.lvl[s] != L) continue;
            const int ds = PL.slot[s];
            float base = winc[s] - tots[s];
#pragma unroll
            for (int k = 0; k < 3; ++k)
                if (k < wv) base += s_w[s][k];
#pragma unroll
            for (int j = 15; j >= 1; --j) S[ds][j] = base + S[ds][j - 1];  // in-place shift
            S[ds][0] = base;
        }
        // ---- reduces whose deepest factor is level L ----
#pragma unroll
        for (int r = 0; r < NROOT; ++r) {
            if (PL.rlvl[r] != L) continue;
            float p[16];
#pragma unroll
            for (int j = 0; j < 16; ++j) p[j] = xr[j];
#pragma unroll
            for (int k = 0; k < 5; ++k) {
                if (k < PL.rnfac[r]) {
                    const int fs = PL.slot[PL.rfac[r][k]];
#pragma unroll
                    for (int j = 0; j < 16; ++j) p[j] *= S[fs][j];
                }
            }
#pragma unroll
            for (int st = 1; st < 16; st <<= 1) {
#pragma unroll
                for (int j = 0; j < 16; j += 2 * st) p[j] += p[j + st];
            }
            const float rt = wave_incl_scan(p[0]);
            if (lane == 63) s_w[NSER + r][wv] = rt;
        }
    }

    __syncthreads();
    if (tid < 32) {
        const int rid = om.m[tid];
        const float T = s_w[NSER + rid][0] + s_w[NSER + rid][1] +
                        s_w[NSER + rid][2] + s_w[NSER + rid][3];
        const float* ap = alphas + tid * 768 + c;  // alphas[tree, i, c] : [32,6,128]
        const float aprod = ap[0] * ap[128] * ap[256] * ap[384] * ap[512] * ap[640];
        out[(((size_t)b << 5) + (size_t)tid) * 128 + c] = aprod * T;
    }
}

// ===========================================================================
extern "C" void kernel_launch(void* const* d_in, const int* in_sizes, int n_in,
                              void* d_out, int out_size, void* d_ws, size_t ws_size,
                              hipStream_t stream) {
    const float* x = (const float*)d_in[0];       // [16,128,4096] f32
    const float* alphas = (const float*)d_in[1];  // [32,6,128]    f32
    float* out = (float*)d_out;                   // [16,32,128]   f32

    OutMap om;
    for (int t = 0; t < cx::NTREE; ++t) om.m[t] = (unsigned char)cx::PL.tree_root[t];

    fis_kernel<<<dim3(16 * 128), dim3(256), 0, stream>>>(x, alphas, out, om);
}